// Round 3
// baseline (1788.001 us; speedup 1.0000x reference)
//
#include <hip/hip_runtime.h>

#define B_ 64
#define T_ 2048
#define I_ 128
#define H_ 128
#define CHUNK 128
#define NCHUNK (T_ / CHUNK)

typedef _Float16 half2v __attribute__((ext_vector_type(2)));

__device__ __forceinline__ float fdot2(unsigned h, unsigned w, float acc) {
#if __has_builtin(__builtin_amdgcn_fdot2)
    return __builtin_amdgcn_fdot2(__builtin_bit_cast(half2v, h),
                                  __builtin_bit_cast(half2v, w), acc, false);
#else
    half2v a = __builtin_bit_cast(half2v, h);
    half2v b = __builtin_bit_cast(half2v, w);
    acc = fmaf((float)a.x, (float)b.x, acc);
    return fmaf((float)a.y, (float)b.y, acc);
#endif
}

__device__ __forceinline__ unsigned pkh(float a, float b) {
    half2v v; v.x = (_Float16)a; v.y = (_Float16)b;
    return __builtin_bit_cast(unsigned, v);
}

// ---------------- Phase 1: xp = x @ W_xh^T + b_xh ----------------
// 1024 blocks x 256 threads; W staged in LDS; 8x8 register tile per thread:
// 256 FMA per (8 global + 8 LDS) b128 loads, k-loop software-pipelined x2.
__global__ __launch_bounds__(256) void xp_gemm(
    const float* __restrict__ x, const float* __restrict__ Wxh,
    const float* __restrict__ bxh, float* __restrict__ xp)
{
    __shared__ float ws[H_ * I_];   // 64 KB, row-major [h][i]
    const int tid = threadIdx.x;
    {
        const float4* src = (const float4*)Wxh;
        float4* dst = (float4*)ws;
        #pragma unroll
        for (int i = 0; i < (H_ * I_ / 4) / 256; ++i)
            dst[tid + i * 256] = src[tid + i * 256];
    }
    __syncthreads();

    const int r0 = (tid >> 4) * 8;            // 8 rows of x
    const int c0 = (tid & 15) * 8;            // 8 output cols (h-dim)
    const float* xb = x + ((size_t)blockIdx.x * 128 + r0) * I_;
    const float* wb = ws + c0 * I_;

    float acc[8][8];
    #pragma unroll
    for (int i = 0; i < 8; ++i)
        #pragma unroll
        for (int j = 0; j < 8; ++j) acc[i][j] = 0.f;

    float4 xa[8], wa[8], xn[8], wn[8];
    #pragma unroll
    for (int i = 0; i < 8; ++i) xa[i] = *(const float4*)(xb + i * I_);
    #pragma unroll
    for (int j = 0; j < 8; ++j) wa[j] = *(const float4*)(wb + j * I_);

    for (int k4 = 0; k4 < 32; k4 += 2) {
        // prefetch k4+1
        #pragma unroll
        for (int i = 0; i < 8; ++i) xn[i] = *(const float4*)(xb + i * I_ + k4 * 4 + 4);
        #pragma unroll
        for (int j = 0; j < 8; ++j) wn[j] = *(const float4*)(wb + j * I_ + k4 * 4 + 4);
        #pragma unroll
        for (int i = 0; i < 8; ++i)
            #pragma unroll
            for (int j = 0; j < 8; ++j) {
                acc[i][j] = fmaf(xa[i].x, wa[j].x, acc[i][j]);
                acc[i][j] = fmaf(xa[i].y, wa[j].y, acc[i][j]);
                acc[i][j] = fmaf(xa[i].z, wa[j].z, acc[i][j]);
                acc[i][j] = fmaf(xa[i].w, wa[j].w, acc[i][j]);
            }
        if (k4 + 2 < 32) {
            #pragma unroll
            for (int i = 0; i < 8; ++i) xa[i] = *(const float4*)(xb + i * I_ + k4 * 4 + 8);
            #pragma unroll
            for (int j = 0; j < 8; ++j) wa[j] = *(const float4*)(wb + j * I_ + k4 * 4 + 8);
        }
        #pragma unroll
        for (int i = 0; i < 8; ++i)
            #pragma unroll
            for (int j = 0; j < 8; ++j) {
                acc[i][j] = fmaf(xn[i].x, wn[j].x, acc[i][j]);
                acc[i][j] = fmaf(xn[i].y, wn[j].y, acc[i][j]);
                acc[i][j] = fmaf(xn[i].z, wn[j].z, acc[i][j]);
                acc[i][j] = fmaf(xn[i].w, wn[j].w, acc[i][j]);
            }
    }

    const float4 b0 = *(const float4*)(bxh + c0);
    const float4 b1 = *(const float4*)(bxh + c0 + 4);
    float* orow = xp + ((size_t)blockIdx.x * 128 + r0) * H_ + c0;
    #pragma unroll
    for (int i = 0; i < 8; ++i) {
        float4 o0, o1;
        o0.x = acc[i][0] + b0.x; o0.y = acc[i][1] + b0.y;
        o0.z = acc[i][2] + b0.z; o0.w = acc[i][3] + b0.w;
        o1.x = acc[i][4] + b1.x; o1.y = acc[i][5] + b1.y;
        o1.z = acc[i][6] + b1.z; o1.w = acc[i][7] + b1.w;
        *(float4*)(orow + i * H_) = o0;
        *(float4*)(orow + i * H_ + 4) = o1;
    }
}

// Stage one 128-step xp chunk (64 KB) into LDS, 64 lanes x 16 B x 64 iters.
__device__ __forceinline__ void stage_chunk64(const float* __restrict__ g,
                                              float* l, int ln)
{
    #pragma unroll
    for (int i = 0; i < 64; ++i) {
        const int off = i * 256;          // floats
        __builtin_amdgcn_global_load_lds(
            (const __attribute__((address_space(1))) unsigned int*)(g + off + ln * 4),
            (__attribute__((address_space(3))) unsigned int*)(l + off),
            16, 0, 0);
    }
}

// ---------------- Phase 2: scan, ONE WAVE per batch ----------------
// Lane l owns outputs 2l, 2l+1; W rows register-resident as packed f16 pairs.
// h exchanged via 256 B packed-f16 LDS buffer (16 broadcast b128 reads/step),
// dot via v_dot2_f32_f16 (f32 accumulate). No barriers; same-wave lgkmcnt only.
__global__ __launch_bounds__(64, 1) void rnn_scan(
    const float* __restrict__ Whh, const float* __restrict__ bhh,
    float* __restrict__ seq /* xp in, h_seq out */, float* __restrict__ hlast)
{
    __shared__ float xpl[2][CHUNK * H_];   // 128 KB
    __shared__ unsigned hpk[2][64];        // packed f16 h, double buffered

    const int l  = threadIdx.x;            // 0..63
    const int b  = blockIdx.x;
    const int j0 = 2 * l;

    unsigned w0[64], w1[64];
    #pragma unroll
    for (int i = 0; i < 64; ++i) {
        const float2 a = *(const float2*)&Whh[(size_t)j0 * H_ + 2 * i];
        const float2 c = *(const float2*)&Whh[(size_t)(j0 + 1) * H_ + 2 * i];
        w0[i] = pkh(a.x, a.y);
        w1[i] = pkh(c.x, c.y);
    }
    const float bj0 = bhh[j0], bj1 = bhh[j0 + 1];
    hpk[0][l] = 0u;
    hpk[1][l] = 0u;

    float* xp = seq + (size_t)b * T_ * H_;
    stage_chunk64(xp, &xpl[0][0], l);      // prologue: chunk 0

    float h0 = 0.f, h1 = 0.f;
    int tg = 0;
    for (int c = 0; c < NCHUNK; ++c) {
        asm volatile("s_waitcnt vmcnt(0)" ::: "memory");   // chunk-c LDS data ready
        if (c + 1 < NCHUNK)
            stage_chunk64(xp + (size_t)(c + 1) * CHUNK * H_, &xpl[(c + 1) & 1][0], l);

        const float* xb = &xpl[c & 1][0];
        float* sq = xp + (size_t)c * CHUNK * H_;

        for (int t = 0; t < CHUNK; ++t, ++tg) {
            const int cur = tg & 1;
            const uint4* hb = (const uint4*)&hpk[cur][0];
            float a00 = bj0, a01 = 0.f, a10 = bj1, a11 = 0.f;
            #pragma unroll
            for (int i = 0; i < 16; ++i) {
                const uint4 hv = hb[i];
                a00 = fdot2(hv.x, w0[4 * i + 0], a00);
                a01 = fdot2(hv.y, w0[4 * i + 1], a01);
                a00 = fdot2(hv.z, w0[4 * i + 2], a00);
                a01 = fdot2(hv.w, w0[4 * i + 3], a01);
                a10 = fdot2(hv.x, w1[4 * i + 0], a10);
                a11 = fdot2(hv.y, w1[4 * i + 1], a11);
                a10 = fdot2(hv.z, w1[4 * i + 2], a10);
                a11 = fdot2(hv.w, w1[4 * i + 3], a11);
            }
            const float2 xc = *(const float2*)&xb[t * H_ + j0];
            const float p0 = xc.x + a00 + a01;
            const float p1 = xc.y + a10 + a11;
            // tanh(x) = 1 - 2/(exp2(x*2*log2e)+1)
            const float e0 = exp2f(p0 * 2.8853900817779268f);
            const float e1 = exp2f(p1 * 2.8853900817779268f);
            h0 = 1.f - 2.f * __builtin_amdgcn_rcpf(e0 + 1.f);
            h1 = 1.f - 2.f * __builtin_amdgcn_rcpf(e1 + 1.f);
            *(float2*)&sq[t * H_ + j0] = make_float2(h0, h1);  // queued global store
            hpk[cur ^ 1][l] = pkh(h0, h1);
            asm volatile("s_waitcnt lgkmcnt(0)" ::: "memory"); // h' visible to next step
        }
    }
    *(float2*)&hlast[b * H_ + j0] = make_float2(h0, h1);
}

extern "C" void kernel_launch(void* const* d_in, const int* in_sizes, int n_in,
                              void* d_out, int out_size, void* d_ws, size_t ws_size,
                              hipStream_t stream)
{
    const float* x   = (const float*)d_in[0];
    const float* Wxh = (const float*)d_in[1];
    const float* bxh = (const float*)d_in[2];
    const float* Whh = (const float*)d_in[3];
    const float* bhh = (const float*)d_in[4];
    float* out   = (float*)d_out;
    float* hlast = out + (size_t)B_ * T_ * H_;

    xp_gemm<<<(B_ * T_) / 128, 256, 0, stream>>>(x, Wxh, bxh, out);
    rnn_scan<<<B_, 64, 0, stream>>>(Whh, bhh, out, hlast);
}

// Round 4
// 1207.934 us; speedup vs baseline: 1.4802x; 1.4802x over previous
//
#include <hip/hip_runtime.h>

#define B_ 64
#define T_ 2048
#define I_ 128
#define H_ 128
#define CHUNK 128
#define NCHUNK (T_ / CHUNK)

typedef _Float16 half2v __attribute__((ext_vector_type(2)));

__device__ __forceinline__ float fdot2(unsigned h, unsigned w, float acc) {
#if __has_builtin(__builtin_amdgcn_fdot2)
    return __builtin_amdgcn_fdot2(__builtin_bit_cast(half2v, h),
                                  __builtin_bit_cast(half2v, w), acc, false);
#else
    half2v a = __builtin_bit_cast(half2v, h);
    half2v b = __builtin_bit_cast(half2v, w);
    acc = fmaf((float)a.x, (float)b.x, acc);
    return fmaf((float)a.y, (float)b.y, acc);
#endif
}

__device__ __forceinline__ unsigned pkh(float a, float b) {
    half2v v; v.x = (_Float16)a; v.y = (_Float16)b;
    return __builtin_bit_cast(unsigned, v);
}

// ---------------- Phase 1: xp = x @ W_xh^T + b_xh ----------------
__global__ __launch_bounds__(256) void xp_gemm(
    const float* __restrict__ x, const float* __restrict__ Wxh,
    const float* __restrict__ bxh, float* __restrict__ xp)
{
    __shared__ float ws[H_ * I_];   // 64 KB, row-major [h][i]
    const int tid = threadIdx.x;
    {
        const float4* src = (const float4*)Wxh;
        float4* dst = (float4*)ws;
        #pragma unroll
        for (int i = 0; i < (H_ * I_ / 4) / 256; ++i)
            dst[tid + i * 256] = src[tid + i * 256];
    }
    __syncthreads();

    const int r0 = (tid >> 4) * 8;
    const int c0 = (tid & 15) * 8;
    const float* xb = x + ((size_t)blockIdx.x * 128 + r0) * I_;
    const float* wb = ws + c0 * I_;

    float acc[8][8];
    #pragma unroll
    for (int i = 0; i < 8; ++i)
        #pragma unroll
        for (int j = 0; j < 8; ++j) acc[i][j] = 0.f;

    float4 xa[8], wa[8], xn[8], wn[8];
    #pragma unroll
    for (int i = 0; i < 8; ++i) xa[i] = *(const float4*)(xb + i * I_);
    #pragma unroll
    for (int j = 0; j < 8; ++j) wa[j] = *(const float4*)(wb + j * I_);

    for (int k4 = 0; k4 < 32; k4 += 2) {
        #pragma unroll
        for (int i = 0; i < 8; ++i) xn[i] = *(const float4*)(xb + i * I_ + k4 * 4 + 4);
        #pragma unroll
        for (int j = 0; j < 8; ++j) wn[j] = *(const float4*)(wb + j * I_ + k4 * 4 + 4);
        #pragma unroll
        for (int i = 0; i < 8; ++i)
            #pragma unroll
            for (int j = 0; j < 8; ++j) {
                acc[i][j] = fmaf(xa[i].x, wa[j].x, acc[i][j]);
                acc[i][j] = fmaf(xa[i].y, wa[j].y, acc[i][j]);
                acc[i][j] = fmaf(xa[i].z, wa[j].z, acc[i][j]);
                acc[i][j] = fmaf(xa[i].w, wa[j].w, acc[i][j]);
            }
        if (k4 + 2 < 32) {
            #pragma unroll
            for (int i = 0; i < 8; ++i) xa[i] = *(const float4*)(xb + i * I_ + k4 * 4 + 8);
            #pragma unroll
            for (int j = 0; j < 8; ++j) wa[j] = *(const float4*)(wb + j * I_ + k4 * 4 + 8);
        }
        #pragma unroll
        for (int i = 0; i < 8; ++i)
            #pragma unroll
            for (int j = 0; j < 8; ++j) {
                acc[i][j] = fmaf(xn[i].x, wn[j].x, acc[i][j]);
                acc[i][j] = fmaf(xn[i].y, wn[j].y, acc[i][j]);
                acc[i][j] = fmaf(xn[i].z, wn[j].z, acc[i][j]);
                acc[i][j] = fmaf(xn[i].w, wn[j].w, acc[i][j]);
            }
    }

    const float4 b0 = *(const float4*)(bxh + c0);
    const float4 b1 = *(const float4*)(bxh + c0 + 4);
    float* orow = xp + ((size_t)blockIdx.x * 128 + r0) * H_ + c0;
    #pragma unroll
    for (int i = 0; i < 8; ++i) {
        float4 o0, o1;
        o0.x = acc[i][0] + b0.x; o0.y = acc[i][1] + b0.y;
        o0.z = acc[i][2] + b0.z; o0.w = acc[i][3] + b0.w;
        o1.x = acc[i][4] + b1.x; o1.y = acc[i][5] + b1.y;
        o1.z = acc[i][6] + b1.z; o1.w = acc[i][7] + b1.w;
        *(float4*)(orow + i * H_) = o0;
        *(float4*)(orow + i * H_ + 4) = o1;
    }
}

// Stage one 128-step xp chunk (64 KB) into LDS, 64 lanes x 16 B x 64 iters.
__device__ __forceinline__ void stage_chunk64(const float* __restrict__ g,
                                              float* l, int ln)
{
    #pragma unroll
    for (int i = 0; i < 64; ++i) {
        const int off = i * 256;
        __builtin_amdgcn_global_load_lds(
            (const __attribute__((address_space(1))) unsigned int*)(g + off + ln * 4),
            (__attribute__((address_space(3))) unsigned int*)(l + off),
            16, 0, 0);
    }
}

// ---- macro repetition: everything NAMED SCALARS so nothing touches scratch ----
#define G16(M) M(0) M(1) M(2) M(3) M(4) M(5) M(6) M(7) \
               M(8) M(9) M(10) M(11) M(12) M(13) M(14) M(15)

#define DECLW(g) unsigned wa##g##_0, wa##g##_1, wa##g##_2, wa##g##_3, \
                          wb##g##_0, wb##g##_1, wb##g##_2, wb##g##_3;
#define LOADW(g) { \
    const float4 xA0 = *(const float4*)(rowA + 8 * g);     \
    const float4 xA1 = *(const float4*)(rowA + 8 * g + 4); \
    wa##g##_0 = pkh(xA0.x, xA0.y); wa##g##_1 = pkh(xA0.z, xA0.w); \
    wa##g##_2 = pkh(xA1.x, xA1.y); wa##g##_3 = pkh(xA1.z, xA1.w); \
    const float4 xB0 = *(const float4*)(rowB + 8 * g);     \
    const float4 xB1 = *(const float4*)(rowB + 8 * g + 4); \
    wb##g##_0 = pkh(xB0.x, xB0.y); wb##g##_1 = pkh(xB0.z, xB0.w); \
    wb##g##_2 = pkh(xB1.x, xB1.y); wb##g##_3 = pkh(xB1.z, xB1.w); }

#define DECLH(g) uint4 hv##g;
#define READH(g) hv##g = hbp[g];
#define DOTG(g) \
    a00 = fdot2(hv##g.x, wa##g##_0, a00); a01 = fdot2(hv##g.y, wa##g##_1, a01); \
    a00 = fdot2(hv##g.z, wa##g##_2, a00); a01 = fdot2(hv##g.w, wa##g##_3, a01); \
    a10 = fdot2(hv##g.x, wb##g##_0, a10); a11 = fdot2(hv##g.y, wb##g##_1, a11); \
    a10 = fdot2(hv##g.z, wb##g##_2, a10); a11 = fdot2(hv##g.w, wb##g##_3, a11);

// ---------------- Phase 2: scan, ONE WAVE per batch ----------------
// Lane l owns outputs 2l, 2l+1. 128 packed-f16 weight dwords live in NAMED
// VGPRs (no arrays -> no scratch). h exchanged as packed f16 via a 256 B LDS
// buffer: 16 broadcast b128 reads + 1 conflict-free b32 write per step.
// Same-wave LDS RAW is DS-pipe-ordered -> no barrier, no lgkmcnt fence.
__global__ __launch_bounds__(64, 1) void rnn_scan(
    const float* __restrict__ Whh, const float* __restrict__ bhh,
    float* __restrict__ seq /* xp in, h_seq out */, float* __restrict__ hlast)
{
    __shared__ float xpl[2][CHUNK * H_];   // 128 KB
    __shared__ unsigned hpk[2][64];        // packed f16 h, double buffered

    const int l = threadIdx.x;             // 0..63
    const int b = blockIdx.x;
    const int j0 = 2 * l;

    const float* rowA = Whh + (size_t)j0 * H_;
    const float* rowB = Whh + (size_t)(j0 + 1) * H_;

    G16(DECLW)
    G16(LOADW)

    const float2 bj = *(const float2*)&bhh[j0];
    const float bj0 = bj.x, bj1 = bj.y;
    hpk[0][l] = 0u;
    hpk[1][l] = 0u;

    float* xp = seq + (size_t)b * T_ * H_;
    stage_chunk64(xp, &xpl[0][0], l);      // prologue: chunk 0

    float h0 = 0.f, h1 = 0.f;
    int tg = 0;
    for (int c = 0; c < NCHUNK; ++c) {
        asm volatile("s_waitcnt vmcnt(0)" ::: "memory");   // chunk-c LDS data ready
        if (c + 1 < NCHUNK)
            stage_chunk64(xp + (size_t)(c + 1) * CHUNK * H_, &xpl[(c + 1) & 1][0], l);

        const float* xb = &xpl[c & 1][0];
        float* sq = xp + (size_t)c * CHUNK * H_;

        for (int t = 0; t < CHUNK; ++t, ++tg) {
            const uint4* hbp = (const uint4*)&hpk[tg & 1][0];
            G16(DECLH)
            G16(READH)                      // 16 broadcast b128; compiler inserts waits
            float a00 = bj0, a01 = 0.f, a10 = bj1, a11 = 0.f;
            G16(DOTG)                       // 128 x v_dot2_f32_f16, 4 indep chains
            const float2 xc = *(const float2*)&xb[t * H_ + j0];
            const float p0 = xc.x + a00 + a01;
            const float p1 = xc.y + a10 + a11;
            // tanh(x) = 1 - 2/(exp2(2x*log2e)+1)
            const float e0 = exp2f(p0 * 2.8853900817779268f);
            const float e1 = exp2f(p1 * 2.8853900817779268f);
            h0 = 1.f - 2.f * __builtin_amdgcn_rcpf(e0 + 1.f);
            h1 = 1.f - 2.f * __builtin_amdgcn_rcpf(e1 + 1.f);
            hpk[(tg & 1) ^ 1][l] = pkh(h0, h1);              // ds_write, next step reads in-order
            *(float2*)&sq[t * H_ + j0] = make_float2(h0, h1); // queued global store
        }
    }
    *(float2*)&hlast[b * H_ + j0] = make_float2(h0, h1);
}

extern "C" void kernel_launch(void* const* d_in, const int* in_sizes, int n_in,
                              void* d_out, int out_size, void* d_ws, size_t ws_size,
                              hipStream_t stream)
{
    const float* x   = (const float*)d_in[0];
    const float* Wxh = (const float*)d_in[1];
    const float* bxh = (const float*)d_in[2];
    const float* Whh = (const float*)d_in[3];
    const float* bhh = (const float*)d_in[4];
    float* out   = (float*)d_out;
    float* hlast = out + (size_t)B_ * T_ * H_;

    xp_gemm<<<(B_ * T_) / 128, 256, 0, stream>>>(x, Wxh, bxh, out);
    rnn_scan<<<B_, 64, 0, stream>>>(Whh, bhh, out, hlast);
}

// Round 5
// 966.804 us; speedup vs baseline: 1.8494x; 1.2494x over previous
//
#include <hip/hip_runtime.h>

#define B_ 64
#define T_ 2048
#define I_ 128
#define H_ 128
#define CHUNK 128
#define NCHUNK (T_ / CHUNK)

typedef _Float16 half2v __attribute__((ext_vector_type(2)));

__device__ __forceinline__ float fdot2(unsigned h, unsigned w, float acc) {
#if __has_builtin(__builtin_amdgcn_fdot2)
    return __builtin_amdgcn_fdot2(__builtin_bit_cast(half2v, h),
                                  __builtin_bit_cast(half2v, w), acc, false);
#else
    half2v a = __builtin_bit_cast(half2v, h);
    half2v b = __builtin_bit_cast(half2v, w);
    acc = fmaf((float)a.x, (float)b.x, acc);
    return fmaf((float)a.y, (float)b.y, acc);
#endif
}

__device__ __forceinline__ unsigned pkh(float a, float b) {
    half2v v; v.x = (_Float16)a; v.y = (_Float16)b;
    return __builtin_bit_cast(unsigned, v);
}

// ---------------- Phase 1: xp = x @ W_xh^T + b_xh ----------------
__global__ __launch_bounds__(256) void xp_gemm(
    const float* __restrict__ x, const float* __restrict__ Wxh,
    const float* __restrict__ bxh, float* __restrict__ xp)
{
    __shared__ float ws[H_ * I_];   // 64 KB, row-major [h][i]
    const int tid = threadIdx.x;
    {
        const float4* src = (const float4*)Wxh;
        float4* dst = (float4*)ws;
        #pragma unroll
        for (int i = 0; i < (H_ * I_ / 4) / 256; ++i)
            dst[tid + i * 256] = src[tid + i * 256];
    }
    __syncthreads();

    const int r0 = (tid >> 4) * 8;
    const int c0 = (tid & 15) * 8;
    const float* xb = x + ((size_t)blockIdx.x * 128 + r0) * I_;
    const float* wb = ws + c0 * I_;

    float acc[8][8];
    #pragma unroll
    for (int i = 0; i < 8; ++i)
        #pragma unroll
        for (int j = 0; j < 8; ++j) acc[i][j] = 0.f;

    float4 xa[8], wa[8], xn[8], wn[8];
    #pragma unroll
    for (int i = 0; i < 8; ++i) xa[i] = *(const float4*)(xb + i * I_);
    #pragma unroll
    for (int j = 0; j < 8; ++j) wa[j] = *(const float4*)(wb + j * I_);

    for (int k4 = 0; k4 < 32; k4 += 2) {
        #pragma unroll
        for (int i = 0; i < 8; ++i) xn[i] = *(const float4*)(xb + i * I_ + k4 * 4 + 4);
        #pragma unroll
        for (int j = 0; j < 8; ++j) wn[j] = *(const float4*)(wb + j * I_ + k4 * 4 + 4);
        #pragma unroll
        for (int i = 0; i < 8; ++i)
            #pragma unroll
            for (int j = 0; j < 8; ++j) {
                acc[i][j] = fmaf(xa[i].x, wa[j].x, acc[i][j]);
                acc[i][j] = fmaf(xa[i].y, wa[j].y, acc[i][j]);
                acc[i][j] = fmaf(xa[i].z, wa[j].z, acc[i][j]);
                acc[i][j] = fmaf(xa[i].w, wa[j].w, acc[i][j]);
            }
        if (k4 + 2 < 32) {
            #pragma unroll
            for (int i = 0; i < 8; ++i) xa[i] = *(const float4*)(xb + i * I_ + k4 * 4 + 8);
            #pragma unroll
            for (int j = 0; j < 8; ++j) wa[j] = *(const float4*)(wb + j * I_ + k4 * 4 + 8);
        }
        #pragma unroll
        for (int i = 0; i < 8; ++i)
            #pragma unroll
            for (int j = 0; j < 8; ++j) {
                acc[i][j] = fmaf(xn[i].x, wn[j].x, acc[i][j]);
                acc[i][j] = fmaf(xn[i].y, wn[j].y, acc[i][j]);
                acc[i][j] = fmaf(xn[i].z, wn[j].z, acc[i][j]);
                acc[i][j] = fmaf(xn[i].w, wn[j].w, acc[i][j]);
            }
    }

    const float4 b0 = *(const float4*)(bxh + c0);
    const float4 b1 = *(const float4*)(bxh + c0 + 4);
    float* orow = xp + ((size_t)blockIdx.x * 128 + r0) * H_ + c0;
    #pragma unroll
    for (int i = 0; i < 8; ++i) {
        float4 o0, o1;
        o0.x = acc[i][0] + b0.x; o0.y = acc[i][1] + b0.y;
        o0.z = acc[i][2] + b0.z; o0.w = acc[i][3] + b0.w;
        o1.x = acc[i][4] + b1.x; o1.y = acc[i][5] + b1.y;
        o1.z = acc[i][6] + b1.z; o1.w = acc[i][7] + b1.w;
        *(float4*)(orow + i * H_) = o0;
        *(float4*)(orow + i * H_ + 4) = o1;
    }
}

// Stage one 128-step xp chunk (64 KB) into LDS with 2 waves.
// Wave w covers dwords [i*512 + w*256, +256) per iter; lds base wave-uniform.
__device__ __forceinline__ void stage_chunk128(const float* __restrict__ g,
                                               float* l, int wv, int ln)
{
    #pragma unroll
    for (int i = 0; i < 32; ++i) {
        const int off = i * 512 + wv * 256;   // dwords, wave-uniform
        __builtin_amdgcn_global_load_lds(
            (const __attribute__((address_space(1))) unsigned int*)(g + off + ln * 4),
            (__attribute__((address_space(3))) unsigned int*)(l + off),
            16, 0, 0);
    }
}

// ---- macro repetition: weights as NAMED, PINNED scalars ----
#define G16(M) M(0) M(1) M(2) M(3) M(4) M(5) M(6) M(7) \
               M(8) M(9) M(10) M(11) M(12) M(13) M(14) M(15)

#define DECLW(g) unsigned w##g##_0, w##g##_1, w##g##_2, w##g##_3;
#define LOADW(g) { \
    const float4 f0 = *(const float4*)(row + 8 * g);     \
    const float4 f1 = *(const float4*)(row + 8 * g + 4); \
    w##g##_0 = pkh(f0.x, f0.y); w##g##_1 = pkh(f0.z, f0.w); \
    w##g##_2 = pkh(f1.x, f1.y); w##g##_3 = pkh(f1.z, f1.w); }
// Non-rematerializable def: allocator must keep these in registers.
#define PINW(g) asm("" : "+v"(w##g##_0), "+v"(w##g##_1), "+v"(w##g##_2), "+v"(w##g##_3));
#define STEPG(g) { \
    const uint4 hv = hbp[g]; \
    a0 = fdot2(hv.x, w##g##_0, a0); \
    a1 = fdot2(hv.y, w##g##_1, a1); \
    a2 = fdot2(hv.z, w##g##_2, a2); \
    a3 = fdot2(hv.w, w##g##_3, a3); }

// ---------------- Phase 2: scan, TWO waves per batch ----------------
// 128 threads; lane tid owns output row j=tid (64 packed-f16 weight dwords,
// pinned in VGPRs). h exchanged as f16 via 256 B LDS buffer: 16 broadcast
// b128 reads + 1 ds_write_b16 per step. Per-step sync: lgkmcnt(0) + raw
// s_barrier (no vmcnt drain -> h_seq global stores stay queued).
__global__ __launch_bounds__(128, 1) void rnn_scan(
    const float* __restrict__ Whh, const float* __restrict__ bhh,
    float* __restrict__ seq /* xp in, h_seq out */, float* __restrict__ hlast)
{
    __shared__ float xpl[2][CHUNK * H_];   // 128 KB
    __shared__ _Float16 hf[2][H_];         // 512 B, double buffered

    const int tid = threadIdx.x;           // 0..127
    const int j   = tid;
    const int b   = blockIdx.x;
    const int wv  = tid >> 6;
    const int ln  = tid & 63;

    const float* row = Whh + (size_t)j * H_;
    G16(DECLW)
    G16(LOADW)
    G16(PINW)

    const float bj = bhh[j];
    hf[0][j] = (_Float16)0.f;
    hf[1][j] = (_Float16)0.f;

    float* xp = seq + (size_t)b * T_ * H_;
    stage_chunk128(xp, &xpl[0][0], wv, ln);   // prologue: chunk 0

    float h = 0.f;
    int tg = 0;
    for (int c = 0; c < NCHUNK; ++c) {
        // my stage loads + my h-init/ds writes done, then cross-wave rendezvous
        asm volatile("s_waitcnt vmcnt(0) lgkmcnt(0)" ::: "memory");
        __builtin_amdgcn_s_barrier();
        if (c + 1 < NCHUNK)
            stage_chunk128(xp + (size_t)(c + 1) * CHUNK * H_, &xpl[(c + 1) & 1][0], wv, ln);

        const float* xb = &xpl[c & 1][0];
        float* sq = xp + (size_t)c * CHUNK * H_;

        for (int t = 0; t < CHUNK; ++t, ++tg) {
            const uint4* hbp = (const uint4*)&hf[tg & 1][0];
            float a0 = bj, a1 = 0.f, a2 = 0.f, a3 = 0.f;
            G16(STEPG)                        // 16 broadcast b128 + 64 dot2
            const float xc = xb[t * H_ + j];
            const float p = xc + ((a0 + a1) + (a2 + a3));
            const float e = exp2f(p * 2.8853900817779268f);
            h = 1.f - 2.f * __builtin_amdgcn_rcpf(e + 1.f);
            hf[(tg & 1) ^ 1][j] = (_Float16)h;     // ds_write_b16
            sq[t * H_ + j] = h;                     // queued global store
            asm volatile("s_waitcnt lgkmcnt(0)" ::: "memory");
            __builtin_amdgcn_s_barrier();           // raw barrier, no vmcnt drain
        }
    }
    hlast[b * H_ + j] = h;
}

extern "C" void kernel_launch(void* const* d_in, const int* in_sizes, int n_in,
                              void* d_out, int out_size, void* d_ws, size_t ws_size,
                              hipStream_t stream)
{
    const float* x   = (const float*)d_in[0];
    const float* Wxh = (const float*)d_in[1];
    const float* bxh = (const float*)d_in[2];
    const float* Whh = (const float*)d_in[3];
    const float* bhh = (const float*)d_in[4];
    float* out   = (float*)d_out;
    float* hlast = out + (size_t)B_ * T_ * H_;

    xp_gemm<<<(B_ * T_) / 128, 256, 0, stream>>>(x, Wxh, bxh, out);
    rnn_scan<<<B_, 128, 0, stream>>>(Whh, bhh, out, hlast);
}